// Round 5
// baseline (321.483 us; speedup 1.0000x reference)
//
#include <hip/hip_runtime.h>
#include <hip/hip_bf16.h>
#include <math.h>

// Problem constants
#define DIM     192
#define HEADS   6
#define HEAD_DIM 32
#define NTOK    64          // tokens per window
#define IN_CC   16
#define TTOT    32768       // 8 * 64 * 64 tokens
#define NWIN    512

using bf16x8 = __attribute__((ext_vector_type(8))) short;
using f32x4  = __attribute__((ext_vector_type(4))) float;
typedef unsigned short ushort_t;

// fp32 -> bf16 round-to-nearest-even (finite inputs)
__device__ __forceinline__ ushort_t f2b(float f) {
    unsigned u = __float_as_uint(f);
    u += 0x7fffu + ((u >> 16) & 1u);
    return (ushort_t)(u >> 16);
}
__device__ __forceinline__ unsigned pk2(float a, float b) {
    return (unsigned)f2b(a) | ((unsigned)f2b(b) << 16);
}

// ---------------------------------------------------------------------------
// Weight fp32 -> bf16 conversion with zero-padding beyond n_src.
// Grid covers padded size / 1024; n_src divisible by 4.
__global__ __launch_bounds__(256) void cvt_kernel(
    const float* __restrict__ src, ushort_t* __restrict__ dst, int n_src)
{
    const int i = (blockIdx.x * 256 + threadIdx.x) * 4;
    ushort4 o;
    if (i < n_src) {
        float4 v = *(const float4*)(src + i);
        o.x = f2b(v.x); o.y = f2b(v.y); o.z = f2b(v.z); o.w = f2b(v.w);
    } else {
        o.x = 0; o.y = 0; o.z = 0; o.w = 0;
    }
    *(ushort4*)(dst + i) = o;
}

// ---------------------------------------------------------------------------
// Kernel 1: LayerNorm1 fused with (B,C,H,W) -> (T,C) transpose.
__global__ __launch_bounds__(256) void ln1_kernel(
    const float* __restrict__ x, const float* __restrict__ g,
    const float* __restrict__ bb, float* __restrict__ outp,
    ushort_t* __restrict__ outh)
{
    __shared__ float xs[64][193];
    __shared__ float mu_s[64], rs_s[64];
    __shared__ float gs[192], bs[192];
    const int tid = threadIdx.x;
    const int t0  = blockIdx.x * 64;
    const int b   = t0 >> 12;
    const int hw0 = t0 & 4095;
    if (tid < 192) { gs[tid] = g[tid]; bs[tid] = bb[tid]; }
    const int tok = tid & 63, qq = tid >> 6;
    const float* xb = x + (size_t)b * (DIM * 4096) + hw0 + tok;
    #pragma unroll
    for (int it = 0; it < 48; ++it) {
        int c = it * 4 + qq;
        xs[tok][c] = xb[(size_t)c * 4096];
    }
    __syncthreads();
    const int tok2 = tid >> 2, p = tid & 3;
    float sum = 0.f;
    #pragma unroll
    for (int c = 0; c < 48; ++c) sum += xs[tok2][p * 48 + c];
    sum += __shfl_xor(sum, 1);
    sum += __shfl_xor(sum, 2);
    const float m = sum * (1.0f / 192.0f);
    float ss = 0.f;
    #pragma unroll
    for (int c = 0; c < 48; ++c) { float d = xs[tok2][p * 48 + c] - m; ss += d * d; }
    ss += __shfl_xor(ss, 1);
    ss += __shfl_xor(ss, 2);
    if (p == 0) {
        mu_s[tok2] = m;
        rs_s[tok2] = 1.0f / sqrtf(ss * (1.0f / 192.0f) + 1e-5f);
    }
    __syncthreads();
    float* ob = outp + (size_t)t0 * DIM;
    ushort_t* obh = outh + (size_t)t0 * DIM;
    #pragma unroll
    for (int it = 0; it < 48; ++it) {
        int idx = it * 256 + tid;
        int tk = idx / 192, c = idx % 192;
        float v = (xs[tk][c] - mu_s[tk]) * rs_s[tk] * gs[c] + bs[c];
        ob[idx] = v;
        obh[idx] = f2b(v);
    }
}

// ---------------------------------------------------------------------------
// MFMA bf16 GEMM, 128x128 tile, 4 waves (each 64x64 via 4x4 16x16x32 mfma).
// A (T,K) bf16; W padded to Npad rows (zeros beyond N), row stride K.
// out/res row stride N (real). Stores guarded by orow < N.
// epi: 0=bias->f32, 1=bias+res->f32, 2=bias+gelu->bf16, 3=bias->bf16
__global__ __launch_bounds__(256) void gemm_mfma(
    const ushort_t* __restrict__ A, const ushort_t* __restrict__ W,
    const float* __restrict__ bias, const float* __restrict__ res,
    float* __restrict__ outf, ushort_t* __restrict__ outh,
    int N, int K, int epi)
{
    __shared__ ushort_t As[128][72];
    __shared__ ushort_t Bs[128][72];
    const int tid  = threadIdx.x;
    const int wave = tid >> 6, lane = tid & 63;
    const int m16  = lane & 15, quad = lane >> 4;
    const int wr   = (wave >> 1) * 64, wc = (wave & 1) * 64;
    const int t0   = blockIdx.x * 128, o0 = blockIdx.y * 128;

    f32x4 acc[4][4];
    #pragma unroll
    for (int i = 0; i < 4; ++i)
        #pragma unroll
        for (int j = 0; j < 4; ++j)
            acc[i][j] = (f32x4)(0.0f);

    for (int k0 = 0; k0 < K; k0 += 64) {
        #pragma unroll
        for (int l = 0; l < 4; ++l) {
            int idx = l * 256 + tid;            // 0..1023: 128 rows x 8 chunks
            int row = idx >> 3, c8 = (idx & 7) * 8;
            *(uint4*)&As[row][c8] = *(const uint4*)&A[(size_t)(t0 + row) * K + k0 + c8];
            *(uint4*)&Bs[row][c8] = *(const uint4*)&W[(size_t)(o0 + row) * K + k0 + c8];
        }
        __syncthreads();
        #pragma unroll
        for (int ks = 0; ks < 64; ks += 32) {
            bf16x8 av[4], bv[4];
            #pragma unroll
            for (int i = 0; i < 4; ++i)
                av[i] = *(const bf16x8*)&As[wr + 16 * i + m16][ks + quad * 8];
            #pragma unroll
            for (int j = 0; j < 4; ++j)
                bv[j] = *(const bf16x8*)&Bs[wc + 16 * j + m16][ks + quad * 8];
            #pragma unroll
            for (int i = 0; i < 4; ++i)
                #pragma unroll
                for (int j = 0; j < 4; ++j)
                    acc[i][j] = __builtin_amdgcn_mfma_f32_16x16x32_bf16(av[i], bv[j], acc[i][j], 0, 0, 0);
        }
        __syncthreads();
    }

    #pragma unroll
    for (int j = 0; j < 4; ++j) {
        const int orow = o0 + wc + 16 * j + m16;
        const bool ok  = orow < N;
        const float bv = ok ? bias[orow] : 0.0f;
        if (!ok) continue;
        #pragma unroll
        for (int i = 0; i < 4; ++i) {
            #pragma unroll
            for (int r = 0; r < 4; ++r) {
                const int trow = t0 + wr + 16 * i + quad * 4 + r;
                float v = acc[i][j][r] + bv;
                if (epi == 1) {
                    v += res[(size_t)trow * N + orow];
                    outf[(size_t)trow * N + orow] = v;
                } else if (epi == 2) {
                    v = 0.5f * v * (1.0f + erff(v * 0.7071067811865475f));
                    outh[(size_t)trow * N + orow] = f2b(v);
                } else if (epi == 3) {
                    outh[(size_t)trow * N + orow] = f2b(v);
                } else {
                    outf[(size_t)trow * N + orow] = v;
                }
            }
        }
    }
}

// ---------------------------------------------------------------------------
// Kernel 3: windowed cosine attention, bf16 qkv input, ~15.7 KB LDS.
__global__ __launch_bounds__(64) void attn_mfma_kernel(
    const ushort_t* __restrict__ qkvh, const float* __restrict__ rpb_table,
    const float* __restrict__ temp, ushort_t* __restrict__ outb)
{
    __shared__ __align__(16) char smem[16016];
    ushort_t* Qh  = (ushort_t*)smem;
    ushort_t* Kh  = (ushort_t*)(smem + 5120);
    float*    Ss  = (float*)smem;
    ushort_t* Pl  = (ushort_t*)smem;
    ushort_t* Vt  = (ushort_t*)(smem + 10240);
    float*    ksb = (float*)(smem + 14848);
    float*    rpb = (float*)(smem + 15104);

    const int n   = threadIdx.x;
    const int win = blockIdx.x;
    const int h   = blockIdx.y;
    const int b   = win >> 6;
    const int wh  = (win >> 3) & 7, ww = win & 7;
    const int i1  = n >> 3, j1 = n & 7;
    const int t   = b * 4096 + (wh * 8 + i1) * 64 + (ww * 8 + j1);
    const ushort_t* base = qkvh + (size_t)t * 576 + h * 32;
    const int m16 = n & 15, quad = n >> 4;

    unsigned qu[16], ku[16], vu[16];
    #pragma unroll
    for (int c = 0; c < 4; ++c) {
        ((uint4*)qu)[c] = *(const uint4*)(base + 8 * c);
        ((uint4*)ku)[c] = *(const uint4*)(base + 192 + 8 * c);
        ((uint4*)vu)[c] = *(const uint4*)(base + 384 + 8 * c);
    }
    float sq = 0.f, sk = 0.f;
    #pragma unroll
    for (int c = 0; c < 16; ++c) {
        float a0 = __uint_as_float(qu[c] << 16);
        float a1 = __uint_as_float(qu[c] & 0xffff0000u);
        sq += a0 * a0 + a1 * a1;
        float b0 = __uint_as_float(ku[c] << 16);
        float b1 = __uint_as_float(ku[c] & 0xffff0000u);
        sk += b0 * b0 + b1 * b1;
    }
    const float qs  = temp[h] / fmaxf(sqrtf(sq), 1e-12f);
    const float ksc = 1.0f / fmaxf(sqrtf(sk), 1e-12f);

    #pragma unroll
    for (int c = 0; c < 4; ++c) {
        *(uint4*)&Qh[n * 40 + 8 * c] = ((uint4*)qu)[c];
        *(uint4*)&Kh[n * 40 + 8 * c] = ((uint4*)ku)[c];
    }
    const int vslot = 4 * m16 + quad;    // slot(m) = 4*(m&15) + (m>>4)
    #pragma unroll
    for (int d = 0; d < 16; ++d) {
        Vt[(2 * d) * 72 + vslot]     = (ushort_t)(vu[d] & 0xffffu);
        Vt[(2 * d + 1) * 72 + vslot] = (ushort_t)(vu[d] >> 16);
    }
    ksb[vslot] = ksc;
    for (int r = n; r < 225; r += 64) rpb[r] = rpb_table[r * 6 + h];
    __syncthreads();

    bf16x8 aq[4], bk[4];
    #pragma unroll
    for (int i = 0; i < 4; ++i) aq[i] = *(const bf16x8*)&Qh[(16*i + m16) * 40 + quad * 8];
    #pragma unroll
    for (int j = 0; j < 4; ++j) bk[j] = *(const bf16x8*)&Kh[(16*j + m16) * 40 + quad * 8];
    f32x4 acc[4][4];
    #pragma unroll
    for (int i = 0; i < 4; ++i)
        #pragma unroll
        for (int j = 0; j < 4; ++j)
            acc[i][j] = __builtin_amdgcn_mfma_f32_16x16x32_bf16(aq[i], bk[j], (f32x4)(0.0f), 0, 0, 0);
    __syncthreads();

    float s[64];
    #pragma unroll
    for (int i = 0; i < 2; ++i)
        #pragma unroll
        for (int r = 0; r < 4; ++r) {
            f32x4 vv = { acc[i][0][r], acc[i][1][r], acc[i][2][r], acc[i][3][r] };
            *(f32x4*)&Ss[(16 * i + 4 * quad + r) * 68 + 4 * m16] = vv;
        }
    __syncthreads();
    if (n < 32) {
        #pragma unroll
        for (int c = 0; c < 16; ++c)
            *(float4*)&s[4 * c] = *(const float4*)&Ss[n * 68 + 4 * c];
    }
    __syncthreads();
    #pragma unroll
    for (int i = 2; i < 4; ++i)
        #pragma unroll
        for (int r = 0; r < 4; ++r) {
            f32x4 vv = { acc[i][0][r], acc[i][1][r], acc[i][2][r], acc[i][3][r] };
            *(f32x4*)&Ss[(16 * (i - 2) + 4 * quad + r) * 68 + 4 * m16] = vv;
        }
    __syncthreads();
    if (n >= 32) {
        #pragma unroll
        for (int c = 0; c < 16; ++c)
            *(float4*)&s[4 * c] = *(const float4*)&Ss[(n - 32) * 68 + 4 * c];
    }

    #pragma unroll
    for (int c = 0; c < 16; ++c) {
        float4 kv = *(const float4*)&ksb[4 * c];
        s[4*c+0] *= qs * kv.x; s[4*c+1] *= qs * kv.y;
        s[4*c+2] *= qs * kv.z; s[4*c+3] *= qs * kv.w;
    }

    float thr = 1e30f;
    for (int it = 0; it < IN_CC; ++it) {
        float mx = -1e30f;
        #pragma unroll
        for (int m = 0; m < 64; ++m) {
            float vv = (s[m] < thr) ? s[m] : -1e30f;
            mx = fmaxf(mx, vv);
        }
        thr = mx;
    }

    const int basen = i1 * 15 + j1;
    float mx = -1e30f;
    #pragma unroll
    for (int c = 0; c < 64; ++c) {
        const int m = 16 * (c & 3) + (c >> 2);
        const int i2 = m >> 3, j2 = m & 7;
        float vv = ((s[c] >= thr) ? s[c] : -100.0f)
                 + rpb[basen + (7 - i2) * 15 + (7 - j2)];
        s[c] = vv;
        mx = fmaxf(mx, vv);
    }
    float sum = 0.f;
    #pragma unroll
    for (int c = 0; c < 64; ++c) { float e = __expf(s[c] - mx); s[c] = e; sum += e; }
    const float inv = 1.0f / sum;
    #pragma unroll
    for (int c = 0; c < 64; ++c) s[c] *= inv;

    __syncthreads();
    #pragma unroll
    for (int gix = 0; gix < 8; ++gix) {
        uint4 w;
        w.x = pk2(s[8*gix+0], s[8*gix+1]); w.y = pk2(s[8*gix+2], s[8*gix+3]);
        w.z = pk2(s[8*gix+4], s[8*gix+5]); w.w = pk2(s[8*gix+6], s[8*gix+7]);
        *(uint4*)&Pl[n * 72 + 8 * gix] = w;
    }
    __syncthreads();

    f32x4 o[4][2];
    #pragma unroll
    for (int i = 0; i < 4; ++i)
        #pragma unroll
        for (int j2 = 0; j2 < 2; ++j2)
            o[i][j2] = (f32x4)(0.0f);
    #pragma unroll
    for (int kh = 0; kh < 64; kh += 32) {
        bf16x8 pa[4], vb[2];
        #pragma unroll
        for (int i = 0; i < 4; ++i)
            pa[i] = *(const bf16x8*)&Pl[(16*i + m16) * 72 + kh + quad * 8];
        #pragma unroll
        for (int j2 = 0; j2 < 2; ++j2)
            vb[j2] = *(const bf16x8*)&Vt[(16*j2 + m16) * 72 + kh + quad * 8];
        #pragma unroll
        for (int i = 0; i < 4; ++i)
            #pragma unroll
            for (int j2 = 0; j2 < 2; ++j2)
                o[i][j2] = __builtin_amdgcn_mfma_f32_16x16x32_bf16(pa[i], vb[j2], o[i][j2], 0, 0, 0);
    }

    #pragma unroll
    for (int i = 0; i < 4; ++i) {
        #pragma unroll
        for (int r = 0; r < 4; ++r) {
            const int row = 16 * i + 4 * quad + r;
            const int tt  = b * 4096 + (wh * 8 + (row >> 3)) * 64 + ww * 8 + (row & 7);
            ushort_t* op = outb + (size_t)tt * DIM + h * 32;
            op[m16]      = f2b(o[i][0][r]);
            op[m16 + 16] = f2b(o[i][1][r]);
        }
    }
}

// ---------------------------------------------------------------------------
// Kernel 5: LayerNorm2 over (T,192) -> bf16. 1 wave per token (4/block).
__global__ __launch_bounds__(256) void ln2_kernel(
    const float* __restrict__ xin, const float* __restrict__ g,
    const float* __restrict__ bb, ushort_t* __restrict__ outp)
{
    const int tid = threadIdx.x;
    const int t = blockIdx.x * 4 + (tid >> 6);
    const int l = tid & 63;
    const float* rp = xin + (size_t)t * DIM;
    const float v0 = rp[l], v1 = rp[l + 64], v2 = rp[l + 128];
    float sum = v0 + v1 + v2;
    #pragma unroll
    for (int off = 1; off < 64; off <<= 1) sum += __shfl_xor(sum, off);
    const float m = sum * (1.0f / 192.0f);
    const float d0 = v0 - m, d1 = v1 - m, d2 = v2 - m;
    float ss = d0 * d0 + d1 * d1 + d2 * d2;
    #pragma unroll
    for (int off = 1; off < 64; off <<= 1) ss += __shfl_xor(ss, off);
    const float rsg = 1.0f / sqrtf(ss * (1.0f / 192.0f) + 1e-5f);
    ushort_t* op = outp + (size_t)t * DIM;
    op[l]       = f2b(d0 * rsg * g[l]       + bb[l]);
    op[l + 64]  = f2b(d1 * rsg * g[l + 64]  + bb[l + 64]);
    op[l + 128] = f2b(d2 * rsg * g[l + 128] + bb[l + 128]);
}

// ---------------------------------------------------------------------------
// Kernel 8: (T,192) -> (B,192,64,64)
__global__ __launch_bounds__(256) void transpose_kernel(
    const float* __restrict__ y, float* __restrict__ outp)
{
    __shared__ float ts[64][193];
    const int tid = threadIdx.x;
    const int t0 = blockIdx.x * 64;
    const int b = t0 >> 12, hw0 = t0 & 4095;
    const float* yp = y + (size_t)t0 * DIM;
    #pragma unroll
    for (int it = 0; it < 48; ++it) {
        int idx = it * 256 + tid;
        ts[idx / 192][idx % 192] = yp[idx];
    }
    __syncthreads();
    float* ob = outp + (size_t)b * (DIM * 4096) + hw0;
    const int tok = tid & 63, qq = tid >> 6;
    #pragma unroll
    for (int it = 0; it < 48; ++it) {
        int c = it * 4 + qq;
        ob[(size_t)c * 4096 + tok] = ts[tok][c];
    }
}

// ---------------------------------------------------------------------------
extern "C" void kernel_launch(void* const* d_in, const int* in_sizes, int n_in,
                              void* d_out, int out_size, void* d_ws, size_t ws_size,
                              hipStream_t stream)
{
    const float* x        = (const float*)d_in[0];
    const float* norm1_g  = (const float*)d_in[1];
    const float* norm1_b  = (const float*)d_in[2];
    const float* qkv_w    = (const float*)d_in[3];
    const float* qkv_b    = (const float*)d_in[4];
    const float* proj_w   = (const float*)d_in[5];
    const float* proj_b   = (const float*)d_in[6];
    const float* rpbt     = (const float*)d_in[7];
    const float* temp     = (const float*)d_in[8];
    const float* norm2_g  = (const float*)d_in[9];
    const float* norm2_b  = (const float*)d_in[10];
    const float* fc1_w    = (const float*)d_in[11];
    const float* fc1_b    = (const float*)d_in[12];
    const float* fc2_w    = (const float*)d_in[13];
    const float* fc2_b    = (const float*)d_in[14];
    float* out = (float*)d_out;

    // ws layout (bytes):
    //   R0 [0,        25165824)  shortcut f32 -> ybuf f32
    //   R1 [25165824, 37748736)  shortcut bf16 -> hbuf bf16
    //   R2 [37748736, 88080384)  qkvh bf16 (37.7MB) -> a1 bf16 (50.3MB)
    //   R3 [88080384,113246208)  x2 f32
    //   R4 [113246208,125829120) attnout bf16
    //   R5 [125829120,...)       weights bf16 (zero-padded to 128-mult rows)
    char* wsb = (char*)d_ws;
    float*    shortcut   = (float*)wsb;
    ushort_t* shortcut_h = (ushort_t*)(wsb + 25165824);
    ushort_t* qkvh       = (ushort_t*)(wsb + 37748736);
    float*    x2         = (float*)(wsb + 88080384);
    ushort_t* attnout_h  = (ushort_t*)(wsb + 113246208);
    ushort_t* wq  = (ushort_t*)(wsb + 125829120);      // 640x192  = 122880
    ushort_t* wp  = wq + 122880;                       // 256x192  = 49152
    ushort_t* w1  = wp + 49152;                        // 768x192  = 147456
    ushort_t* w2  = w1 + 147456;                       // 256x768  = 196608
    ushort_t* a1    = qkvh;          // reuse R2 (qkvh dead after attn)
    ushort_t* hbuf  = shortcut_h;    // reuse R1
    float*    ybuf  = shortcut;      // reuse R0

    // 0. weight conversions with zero-pad
    hipLaunchKernelGGL(cvt_kernel, dim3(122880 / 1024), dim3(256), 0, stream, qkv_w, wq, 110592);
    hipLaunchKernelGGL(cvt_kernel, dim3(49152  / 1024), dim3(256), 0, stream, proj_w, wp, 36864);
    hipLaunchKernelGGL(cvt_kernel, dim3(147456 / 1024), dim3(256), 0, stream, fc1_w, w1, 147456);
    hipLaunchKernelGGL(cvt_kernel, dim3(196608 / 1024), dim3(256), 0, stream, fc2_w, w2, 147456);

    hipLaunchKernelGGL(ln1_kernel, dim3(TTOT / 64), dim3(256), 0, stream,
                       x, norm1_g, norm1_b, shortcut, shortcut_h);
    // qkv -> bf16 (epi 3), Npad=640
    hipLaunchKernelGGL(gemm_mfma, dim3(TTOT / 128, 5), dim3(256), 0, stream,
                       shortcut_h, wq, qkv_b, (const float*)nullptr,
                       (float*)nullptr, qkvh, 576, 192, 3);
    hipLaunchKernelGGL(attn_mfma_kernel, dim3(NWIN, HEADS), dim3(64), 0, stream,
                       qkvh, rpbt, temp, attnout_h);
    // proj + residual -> f32, Npad=256
    hipLaunchKernelGGL(gemm_mfma, dim3(TTOT / 128, 2), dim3(256), 0, stream,
                       attnout_h, wp, proj_b, shortcut,
                       x2, (ushort_t*)nullptr, 192, 192, 1);
    hipLaunchKernelGGL(ln2_kernel, dim3(TTOT / 4), dim3(256), 0, stream,
                       x2, norm2_g, norm2_b, hbuf);
    // fc1 + gelu -> bf16, N=768 (no pad)
    hipLaunchKernelGGL(gemm_mfma, dim3(TTOT / 128, 6), dim3(256), 0, stream,
                       hbuf, w1, fc1_b, (const float*)nullptr,
                       (float*)nullptr, a1, 768, 192, 2);
    // fc2 + residual -> f32, Npad=256, K=768
    hipLaunchKernelGGL(gemm_mfma, dim3(TTOT / 128, 2), dim3(256), 0, stream,
                       a1, w2, fc2_b, x2, ybuf, (ushort_t*)nullptr, 192, 768, 1);
    hipLaunchKernelGGL(transpose_kernel, dim3(TTOT / 64), dim3(256), 0, stream,
                       ybuf, out);
}

// Round 6
// 248.283 us; speedup vs baseline: 1.2948x; 1.2948x over previous
//
#include <hip/hip_runtime.h>
#include <hip/hip_bf16.h>
#include <math.h>

// Problem constants
#define DIM     192
#define HEADS   6
#define HEAD_DIM 32
#define NTOK    64          // tokens per window
#define IN_CC   16
#define TTOT    32768       // 8 * 64 * 64 tokens
#define NWIN    512

using bf16x8 = __attribute__((ext_vector_type(8))) short;
using f32x4  = __attribute__((ext_vector_type(4))) float;
typedef unsigned short ushort_t;

// fp32 -> bf16 round-to-nearest-even (finite inputs)
__device__ __forceinline__ ushort_t f2b(float f) {
    unsigned u = __float_as_uint(f);
    u += 0x7fffu + ((u >> 16) & 1u);
    return (ushort_t)(u >> 16);
}
__device__ __forceinline__ unsigned pk2(float a, float b) {
    return (unsigned)f2b(a) | ((unsigned)f2b(b) << 16);
}

// ---------------------------------------------------------------------------
// Weight fp32 -> bf16 conversion (n divisible by 1024)
__global__ __launch_bounds__(256) void cvt_kernel(
    const float* __restrict__ src, ushort_t* __restrict__ dst)
{
    const int i = (blockIdx.x * 256 + threadIdx.x) * 4;
    float4 v = *(const float4*)(src + i);
    ushort4 o;
    o.x = f2b(v.x); o.y = f2b(v.y); o.z = f2b(v.z); o.w = f2b(v.w);
    *(ushort4*)(dst + i) = o;
}

// ---------------------------------------------------------------------------
// Kernel 1: LayerNorm1 fused with (B,C,H,W) -> (T,C) transpose.
__global__ __launch_bounds__(256) void ln1_kernel(
    const float* __restrict__ x, const float* __restrict__ g,
    const float* __restrict__ bb, float* __restrict__ outp,
    ushort_t* __restrict__ outh)
{
    __shared__ float xs[64][193];
    __shared__ float mu_s[64], rs_s[64];
    __shared__ float gs[192], bs[192];
    const int tid = threadIdx.x;
    const int t0  = blockIdx.x * 64;
    const int b   = t0 >> 12;
    const int hw0 = t0 & 4095;
    if (tid < 192) { gs[tid] = g[tid]; bs[tid] = bb[tid]; }
    const int tok = tid & 63, qq = tid >> 6;
    const float* xb = x + (size_t)b * (DIM * 4096) + hw0 + tok;
    #pragma unroll
    for (int it = 0; it < 48; ++it) {
        int c = it * 4 + qq;
        xs[tok][c] = xb[(size_t)c * 4096];
    }
    __syncthreads();
    const int tok2 = tid >> 2, p = tid & 3;
    float sum = 0.f;
    #pragma unroll
    for (int c = 0; c < 48; ++c) sum += xs[tok2][p * 48 + c];
    sum += __shfl_xor(sum, 1);
    sum += __shfl_xor(sum, 2);
    const float m = sum * (1.0f / 192.0f);
    float ss = 0.f;
    #pragma unroll
    for (int c = 0; c < 48; ++c) { float d = xs[tok2][p * 48 + c] - m; ss += d * d; }
    ss += __shfl_xor(ss, 1);
    ss += __shfl_xor(ss, 2);
    if (p == 0) {
        mu_s[tok2] = m;
        rs_s[tok2] = 1.0f / sqrtf(ss * (1.0f / 192.0f) + 1e-5f);
    }
    __syncthreads();
    float* ob = outp + (size_t)t0 * DIM;
    ushort_t* obh = outh + (size_t)t0 * DIM;
    #pragma unroll
    for (int it = 0; it < 48; ++it) {
        int idx = it * 256 + tid;
        int tk = idx / 192, c = idx % 192;
        float v = (xs[tk][c] - mu_s[tk]) * rs_s[tk] * gs[c] + bs[c];
        ob[idx] = v;
        obh[idx] = f2b(v);
    }
}

// ---------------------------------------------------------------------------
// MFMA bf16 GEMM, 64x64 tile, 4 waves (each 32x32). N,K divisible by 64.
// All epilogues bounce C through LDS and store coalesced vectors.
// epi: 0=bias->f32, 1=bias+res->f32, 2=bias+gelu->bf16, 3=bias->bf16,
//      4=bias+res->f32 stored TRANSPOSED to (B,C,64,64) NCHW layout.
__global__ __launch_bounds__(256) void gemm_mfma(
    const ushort_t* __restrict__ A, const ushort_t* __restrict__ W,
    const float* __restrict__ bias, const float* __restrict__ res,
    float* __restrict__ outf, ushort_t* __restrict__ outh,
    int N, int K, int epi)
{
    __shared__ __align__(16) char sm[18432];
    ushort_t (*As)[72] = (ushort_t(*)[72])sm;
    ushort_t (*Bs)[72] = (ushort_t(*)[72])(sm + 9216);
    ushort_t (*Ch)[72] = (ushort_t(*)[72])sm;     // bf16 C tile (9216 B)
    float    (*Cf)[68] = (float(*)[68])sm;        // f32 C tile (17408 B)

    const int tid  = threadIdx.x;
    const int wave = tid >> 6, lane = tid & 63;
    const int m16  = lane & 15, quad = lane >> 4;
    const int wr   = (wave >> 1) * 32, wc = (wave & 1) * 32;
    const int t0   = blockIdx.x * 64, o0 = blockIdx.y * 64;

    f32x4 acc[2][2];
    #pragma unroll
    for (int i = 0; i < 2; ++i)
        #pragma unroll
        for (int j = 0; j < 2; ++j)
            acc[i][j] = (f32x4)(0.0f);

    for (int k0 = 0; k0 < K; k0 += 64) {
        #pragma unroll
        for (int l = 0; l < 2; ++l) {
            int idx = l * 256 + tid;            // 0..511: 64 rows x 8 chunks
            int row = idx >> 3, c8 = (idx & 7) * 8;
            *(uint4*)&As[row][c8] = *(const uint4*)&A[(size_t)(t0 + row) * K + k0 + c8];
            *(uint4*)&Bs[row][c8] = *(const uint4*)&W[(size_t)(o0 + row) * K + k0 + c8];
        }
        __syncthreads();
        #pragma unroll
        for (int ks = 0; ks < 64; ks += 32) {
            bf16x8 a0 = *(const bf16x8*)&As[wr + m16][ks + quad * 8];
            bf16x8 a1 = *(const bf16x8*)&As[wr + 16 + m16][ks + quad * 8];
            bf16x8 b0 = *(const bf16x8*)&Bs[wc + m16][ks + quad * 8];
            bf16x8 b1 = *(const bf16x8*)&Bs[wc + 16 + m16][ks + quad * 8];
            acc[0][0] = __builtin_amdgcn_mfma_f32_16x16x32_bf16(a0, b0, acc[0][0], 0, 0, 0);
            acc[0][1] = __builtin_amdgcn_mfma_f32_16x16x32_bf16(a0, b1, acc[0][1], 0, 0, 0);
            acc[1][0] = __builtin_amdgcn_mfma_f32_16x16x32_bf16(a1, b0, acc[1][0], 0, 0, 0);
            acc[1][1] = __builtin_amdgcn_mfma_f32_16x16x32_bf16(a1, b1, acc[1][1], 0, 0, 0);
        }
        __syncthreads();
    }

    // ---- epilogue: bias (+gelu) into LDS C tile ----
    if (epi == 2 || epi == 3) {
        #pragma unroll
        for (int j = 0; j < 2; ++j) {
            const int col = wc + 16 * j + m16;
            const float bv = bias[o0 + col];
            #pragma unroll
            for (int i = 0; i < 2; ++i)
                #pragma unroll
                for (int r = 0; r < 4; ++r) {
                    const int row = wr + 16 * i + quad * 4 + r;
                    float v = acc[i][j][r] + bv;
                    if (epi == 2) v = 0.5f * v * (1.0f + erff(v * 0.7071067811865475f));
                    Ch[row][col] = f2b(v);
                }
        }
        __syncthreads();
        #pragma unroll
        for (int p = 0; p < 2; ++p) {
            const int idx = p * 256 + tid;        // 64 rows x 8 uint4
            const int row = idx >> 3, c8 = (idx & 7) * 8;
            *(uint4*)&outh[(size_t)(t0 + row) * N + o0 + c8] = *(const uint4*)&Ch[row][c8];
        }
    } else {
        #pragma unroll
        for (int j = 0; j < 2; ++j) {
            const int col = wc + 16 * j + m16;
            const float bv = bias[o0 + col];
            #pragma unroll
            for (int i = 0; i < 2; ++i)
                #pragma unroll
                for (int r = 0; r < 4; ++r) {
                    const int row = wr + 16 * i + quad * 4 + r;
                    Cf[row][col] = acc[i][j][r] + bv;
                }
        }
        __syncthreads();
        if (epi == 4) {
            // res (row-major f32 T x N) + transposed store to NCHW
            const int b   = t0 >> 12;
            const int hw0 = t0 & 4095;
            #pragma unroll
            for (int p = 0; p < 4; ++p) {
                const int idx = p * 256 + tid;    // 64 cols x 16 tok4-chunks
                const int c = idx >> 4, t4 = (idx & 15) * 4;
                float4 vv;
                vv.x = Cf[t4 + 0][c] + res[(size_t)(t0 + t4 + 0) * N + o0 + c];
                vv.y = Cf[t4 + 1][c] + res[(size_t)(t0 + t4 + 1) * N + o0 + c];
                vv.z = Cf[t4 + 2][c] + res[(size_t)(t0 + t4 + 2) * N + o0 + c];
                vv.w = Cf[t4 + 3][c] + res[(size_t)(t0 + t4 + 3) * N + o0 + c];
                *(float4*)&outf[(size_t)b * (DIM * 4096) + (size_t)(o0 + c) * 4096 + hw0 + t4] = vv;
            }
        } else {
            #pragma unroll
            for (int p = 0; p < 4; ++p) {
                const int idx = p * 256 + tid;    // 64 rows x 16 float4
                const int row = idx >> 4, c4 = (idx & 15) * 4;
                float4 vv = *(const float4*)&Cf[row][c4];
                if (epi == 1) {
                    const float4 rv = *(const float4*)&res[(size_t)(t0 + row) * N + o0 + c4];
                    vv.x += rv.x; vv.y += rv.y; vv.z += rv.z; vv.w += rv.w;
                }
                *(float4*)&outf[(size_t)(t0 + row) * N + o0 + c4] = vv;
            }
        }
    }
}

// ---------------------------------------------------------------------------
// Kernel 3: windowed cosine attention, bf16 qkv input, ~15.7 KB LDS.
__global__ __launch_bounds__(64) void attn_mfma_kernel(
    const ushort_t* __restrict__ qkvh, const float* __restrict__ rpb_table,
    const float* __restrict__ temp, ushort_t* __restrict__ outb)
{
    __shared__ __align__(16) char smem[16016];
    ushort_t* Qh  = (ushort_t*)smem;
    ushort_t* Kh  = (ushort_t*)(smem + 5120);
    float*    Ss  = (float*)smem;
    ushort_t* Pl  = (ushort_t*)smem;
    ushort_t* Vt  = (ushort_t*)(smem + 10240);
    float*    ksb = (float*)(smem + 14848);
    float*    rpb = (float*)(smem + 15104);

    const int n   = threadIdx.x;
    const int win = blockIdx.x;
    const int h   = blockIdx.y;
    const int b   = win >> 6;
    const int wh  = (win >> 3) & 7, ww = win & 7;
    const int i1  = n >> 3, j1 = n & 7;
    const int t   = b * 4096 + (wh * 8 + i1) * 64 + (ww * 8 + j1);
    const ushort_t* base = qkvh + (size_t)t * 576 + h * 32;
    const int m16 = n & 15, quad = n >> 4;

    unsigned qu[16], ku[16], vu[16];
    #pragma unroll
    for (int c = 0; c < 4; ++c) {
        ((uint4*)qu)[c] = *(const uint4*)(base + 8 * c);
        ((uint4*)ku)[c] = *(const uint4*)(base + 192 + 8 * c);
        ((uint4*)vu)[c] = *(const uint4*)(base + 384 + 8 * c);
    }
    float sq = 0.f, sk = 0.f;
    #pragma unroll
    for (int c = 0; c < 16; ++c) {
        float a0 = __uint_as_float(qu[c] << 16);
        float a1 = __uint_as_float(qu[c] & 0xffff0000u);
        sq += a0 * a0 + a1 * a1;
        float b0 = __uint_as_float(ku[c] << 16);
        float b1 = __uint_as_float(ku[c] & 0xffff0000u);
        sk += b0 * b0 + b1 * b1;
    }
    const float qs  = temp[h] / fmaxf(sqrtf(sq), 1e-12f);
    const float ksc = 1.0f / fmaxf(sqrtf(sk), 1e-12f);

    #pragma unroll
    for (int c = 0; c < 4; ++c) {
        *(uint4*)&Qh[n * 40 + 8 * c] = ((uint4*)qu)[c];
        *(uint4*)&Kh[n * 40 + 8 * c] = ((uint4*)ku)[c];
    }
    const int vslot = 4 * m16 + quad;    // slot(m) = 4*(m&15) + (m>>4)
    #pragma unroll
    for (int d = 0; d < 16; ++d) {
        Vt[(2 * d) * 72 + vslot]     = (ushort_t)(vu[d] & 0xffffu);
        Vt[(2 * d + 1) * 72 + vslot] = (ushort_t)(vu[d] >> 16);
    }
    ksb[vslot] = ksc;
    for (int r = n; r < 225; r += 64) rpb[r] = rpb_table[r * 6 + h];
    __syncthreads();

    bf16x8 aq[4], bk[4];
    #pragma unroll
    for (int i = 0; i < 4; ++i) aq[i] = *(const bf16x8*)&Qh[(16*i + m16) * 40 + quad * 8];
    #pragma unroll
    for (int j = 0; j < 4; ++j) bk[j] = *(const bf16x8*)&Kh[(16*j + m16) * 40 + quad * 8];
    f32x4 acc[4][4];
    #pragma unroll
    for (int i = 0; i < 4; ++i)
        #pragma unroll
        for (int j = 0; j < 4; ++j)
            acc[i][j] = __builtin_amdgcn_mfma_f32_16x16x32_bf16(aq[i], bk[j], (f32x4)(0.0f), 0, 0, 0);
    __syncthreads();

    float s[64];
    #pragma unroll
    for (int i = 0; i < 2; ++i)
        #pragma unroll
        for (int r = 0; r < 4; ++r) {
            f32x4 vv = { acc[i][0][r], acc[i][1][r], acc[i][2][r], acc[i][3][r] };
            *(f32x4*)&Ss[(16 * i + 4 * quad + r) * 68 + 4 * m16] = vv;
        }
    __syncthreads();
    if (n < 32) {
        #pragma unroll
        for (int c = 0; c < 16; ++c)
            *(float4*)&s[4 * c] = *(const float4*)&Ss[n * 68 + 4 * c];
    }
    __syncthreads();
    #pragma unroll
    for (int i = 2; i < 4; ++i)
        #pragma unroll
        for (int r = 0; r < 4; ++r) {
            f32x4 vv = { acc[i][0][r], acc[i][1][r], acc[i][2][r], acc[i][3][r] };
            *(f32x4*)&Ss[(16 * (i - 2) + 4 * quad + r) * 68 + 4 * m16] = vv;
        }
    __syncthreads();
    if (n >= 32) {
        #pragma unroll
        for (int c = 0; c < 16; ++c)
            *(float4*)&s[4 * c] = *(const float4*)&Ss[(n - 32) * 68 + 4 * c];
    }

    #pragma unroll
    for (int c = 0; c < 16; ++c) {
        float4 kv = *(const float4*)&ksb[4 * c];
        s[4*c+0] *= qs * kv.x; s[4*c+1] *= qs * kv.y;
        s[4*c+2] *= qs * kv.z; s[4*c+3] *= qs * kv.w;
    }

    float thr = 1e30f;
    for (int it = 0; it < IN_CC; ++it) {
        float mx = -1e30f;
        #pragma unroll
        for (int m = 0; m < 64; ++m) {
            float vv = (s[m] < thr) ? s[m] : -1e30f;
            mx = fmaxf(mx, vv);
        }
        thr = mx;
    }

    const int basen = i1 * 15 + j1;
    float mx = -1e30f;
    #pragma unroll
    for (int c = 0; c < 64; ++c) {
        const int m = 16 * (c & 3) + (c >> 2);
        const int i2 = m >> 3, j2 = m & 7;
        float vv = ((s[c] >= thr) ? s[c] : -100.0f)
                 + rpb[basen + (7 - i2) * 15 + (7 - j2)];
        s[c] = vv;
        mx = fmaxf(mx, vv);
    }
    float sum = 0.f;
    #pragma unroll
    for (int c = 0; c < 64; ++c) { float e = __expf(s[c] - mx); s[c] = e; sum += e; }
    const float inv = 1.0f / sum;
    #pragma unroll
    for (int c = 0; c < 64; ++c) s[c] *= inv;

    __syncthreads();
    #pragma unroll
    for (int gix = 0; gix < 8; ++gix) {
        uint4 w;
        w.x = pk2(s[8*gix+0], s[8*gix+1]); w.y = pk2(s[8*gix+2], s[8*gix+3]);
        w.z = pk2(s[8*gix+4], s[8*gix+5]); w.w = pk2(s[8*gix+6], s[8*gix+7]);
        *(uint4*)&Pl[n * 72 + 8 * gix] = w;
    }
    __syncthreads();

    f32x4 o[4][2];
    #pragma unroll
    for (int i = 0; i < 4; ++i)
        #pragma unroll
        for (int j2 = 0; j2 < 2; ++j2)
            o[i][j2] = (f32x4)(0.0f);
    #pragma unroll
    for (int kh = 0; kh < 64; kh += 32) {
        bf16x8 pa[4], vb[2];
        #pragma unroll
        for (int i = 0; i < 4; ++i)
            pa[i] = *(const bf16x8*)&Pl[(16*i + m16) * 72 + kh + quad * 8];
        #pragma unroll
        for (int j2 = 0; j2 < 2; ++j2)
            vb[j2] = *(const bf16x8*)&Vt[(16*j2 + m16) * 72 + kh + quad * 8];
        #pragma unroll
        for (int i = 0; i < 4; ++i)
            #pragma unroll
            for (int j2 = 0; j2 < 2; ++j2)
                o[i][j2] = __builtin_amdgcn_mfma_f32_16x16x32_bf16(pa[i], vb[j2], o[i][j2], 0, 0, 0);
    }

    #pragma unroll
    for (int i = 0; i < 4; ++i) {
        #pragma unroll
        for (int r = 0; r < 4; ++r) {
            const int row = 16 * i + 4 * quad + r;
            const int tt  = b * 4096 + (wh * 8 + (row >> 3)) * 64 + ww * 8 + (row & 7);
            ushort_t* op = outb + (size_t)tt * DIM + h * 32;
            op[m16]      = f2b(o[i][0][r]);
            op[m16 + 16] = f2b(o[i][1][r]);
        }
    }
}

// ---------------------------------------------------------------------------
// Kernel 5: LayerNorm2 over (T,192) -> bf16. 1 wave per token (4/block).
__global__ __launch_bounds__(256) void ln2_kernel(
    const float* __restrict__ xin, const float* __restrict__ g,
    const float* __restrict__ bb, ushort_t* __restrict__ outp)
{
    const int tid = threadIdx.x;
    const int t = blockIdx.x * 4 + (tid >> 6);
    const int l = tid & 63;
    const float* rp = xin + (size_t)t * DIM;
    const float v0 = rp[l], v1 = rp[l + 64], v2 = rp[l + 128];
    float sum = v0 + v1 + v2;
    #pragma unroll
    for (int off = 1; off < 64; off <<= 1) sum += __shfl_xor(sum, off);
    const float m = sum * (1.0f / 192.0f);
    const float d0 = v0 - m, d1 = v1 - m, d2 = v2 - m;
    float ss = d0 * d0 + d1 * d1 + d2 * d2;
    #pragma unroll
    for (int off = 1; off < 64; off <<= 1) ss += __shfl_xor(ss, off);
    const float rsg = 1.0f / sqrtf(ss * (1.0f / 192.0f) + 1e-5f);
    ushort_t* op = outp + (size_t)t * DIM;
    op[l]       = f2b(d0 * rsg * g[l]       + bb[l]);
    op[l + 64]  = f2b(d1 * rsg * g[l + 64]  + bb[l + 64]);
    op[l + 128] = f2b(d2 * rsg * g[l + 128] + bb[l + 128]);
}

// ---------------------------------------------------------------------------
extern "C" void kernel_launch(void* const* d_in, const int* in_sizes, int n_in,
                              void* d_out, int out_size, void* d_ws, size_t ws_size,
                              hipStream_t stream)
{
    const float* x        = (const float*)d_in[0];
    const float* norm1_g  = (const float*)d_in[1];
    const float* norm1_b  = (const float*)d_in[2];
    const float* qkv_w    = (const float*)d_in[3];
    const float* qkv_b    = (const float*)d_in[4];
    const float* proj_w   = (const float*)d_in[5];
    const float* proj_b   = (const float*)d_in[6];
    const float* rpbt     = (const float*)d_in[7];
    const float* temp     = (const float*)d_in[8];
    const float* norm2_g  = (const float*)d_in[9];
    const float* norm2_b  = (const float*)d_in[10];
    const float* fc1_w    = (const float*)d_in[11];
    const float* fc1_b    = (const float*)d_in[12];
    const float* fc2_w    = (const float*)d_in[13];
    const float* fc2_b    = (const float*)d_in[14];
    float* out = (float*)d_out;

    // ws layout (bytes):
    //   R0 [0,        25165824)  shortcut f32
    //   R1 [25165824, 37748736)  shortcut bf16 -> hbuf bf16
    //   R2 [37748736, 88080384)  qkvh bf16 (37.7MB) -> a1 bf16 (50.3MB)
    //   R3 [88080384,113246208)  x2 f32
    //   R4 [113246208,125829120) attnout bf16
    //   R5 [125829120,...)       weights bf16
    char* wsb = (char*)d_ws;
    float*    shortcut   = (float*)wsb;
    ushort_t* shortcut_h = (ushort_t*)(wsb + 25165824);
    ushort_t* qkvh       = (ushort_t*)(wsb + 37748736);
    float*    x2         = (float*)(wsb + 88080384);
    ushort_t* attnout_h  = (ushort_t*)(wsb + 113246208);
    ushort_t* wq  = (ushort_t*)(wsb + 125829120);      // 576x192 = 110592
    ushort_t* wp  = wq + 110592;                       // 192x192 = 36864
    ushort_t* w1  = wp + 36864;                        // 768x192 = 147456
    ushort_t* w2  = w1 + 147456;                       // 192x768 = 147456
    ushort_t* a1    = qkvh;          // reuse R2 (qkvh dead after attn)
    ushort_t* hbuf  = shortcut_h;    // reuse R1

    // 0. weight conversions (fp32 -> bf16)
    hipLaunchKernelGGL(cvt_kernel, dim3(110592 / 1024), dim3(256), 0, stream, qkv_w, wq);
    hipLaunchKernelGGL(cvt_kernel, dim3(36864  / 1024), dim3(256), 0, stream, proj_w, wp);
    hipLaunchKernelGGL(cvt_kernel, dim3(147456 / 1024), dim3(256), 0, stream, fc1_w, w1);
    hipLaunchKernelGGL(cvt_kernel, dim3(147456 / 1024), dim3(256), 0, stream, fc2_w, w2);

    // 1. LN1 + transpose -> shortcut f32 + bf16
    hipLaunchKernelGGL(ln1_kernel, dim3(TTOT / 64), dim3(256), 0, stream,
                       x, norm1_g, norm1_b, shortcut, shortcut_h);
    // 2. qkv -> bf16 (epi 3)
    hipLaunchKernelGGL(gemm_mfma, dim3(TTOT / 64, 9), dim3(256), 0, stream,
                       shortcut_h, wq, qkv_b, (const float*)nullptr,
                       (float*)nullptr, qkvh, 576, 192, 3);
    // 3. attention -> attnout bf16
    hipLaunchKernelGGL(attn_mfma_kernel, dim3(NWIN, HEADS), dim3(64), 0, stream,
                       qkvh, rpbt, temp, attnout_h);
    // 4. x2 = attnout @ proj^T + b + shortcut (epi 1)
    hipLaunchKernelGGL(gemm_mfma, dim3(TTOT / 64, 3), dim3(256), 0, stream,
                       attnout_h, wp, proj_b, shortcut,
                       x2, (ushort_t*)nullptr, 192, 192, 1);
    // 5. h = LN2(x2) -> bf16
    hipLaunchKernelGGL(ln2_kernel, dim3(TTOT / 4), dim3(256), 0, stream,
                       x2, norm2_g, norm2_b, hbuf);
    // 6. a1 = gelu(h @ fc1^T + b) -> bf16 (epi 2)
    hipLaunchKernelGGL(gemm_mfma, dim3(TTOT / 64, 12), dim3(256), 0, stream,
                       hbuf, w1, fc1_b, (const float*)nullptr,
                       (float*)nullptr, a1, 768, 192, 2);
    // 7. y = a1 @ fc2^T + b + x2, stored transposed to NCHW out (epi 4)
    hipLaunchKernelGGL(gemm_mfma, dim3(TTOT / 64, 3), dim3(256), 0, stream,
                       a1, w2, fc2_b, x2, out, (ushort_t*)nullptr, 192, 768, 4);
}